// Round 7
// baseline (895.766 us; speedup 1.0000x reference)
//
#include <hip/hip_runtime.h>
#include <cstdint>
#include <cstddef>

#define B_     4
#define L_     5000
#define H_     256
#define W_     256
#define HW_    65536
#define CIN_   256
#define DLOI_  128
#define NPTS0_ 32
#define NPTS1_ 8
#define DFC_   1024
#define NOUT_  2500
#define M_     (B_*L_)   // 20000
#define MPAD_  20096     // 157 * 128
#define NBAND_ 157       // MPAD_/128

typedef _Float16 f16;
typedef _Float16 f16x4 __attribute__((ext_vector_type(4)));
typedef _Float16 f16x8 __attribute__((ext_vector_type(8)));
typedef float    f32x4 __attribute__((ext_vector_type(4)));

__device__ __forceinline__ void gload16(const void* g, void* l) {
  __builtin_amdgcn_global_load_lds(
      (const __attribute__((address_space(1))) void*)g,
      (__attribute__((address_space(3))) void*)l, 16, 0, 0);
}

// ---------------------------------------------------------------------------
// K0a: split fc1_w [128][256] fp32 -> f16 hi/lo planes (same [n][k] layout)
// ---------------------------------------------------------------------------
__global__ __launch_bounds__(256) void k_wsplit(const float* __restrict__ src,
                                                f16* __restrict__ h,
                                                f16* __restrict__ l) {
  int i = (blockIdx.x * 256 + threadIdx.x) * 4;
  float4 v = *(const float4*)(src + i);
  f16 h0 = (f16)v.x, h1 = (f16)v.y, h2 = (f16)v.z, h3 = (f16)v.w;
  *(f16x4*)(h + i) = (f16x4){h0, h1, h2, h3};
  *(f16x4*)(l + i) = (f16x4){(f16)(v.x - (float)h0), (f16)(v.y - (float)h1),
                             (f16)(v.z - (float)h2), (f16)(v.w - (float)h3)};
}

// ---------------------------------------------------------------------------
// K0b: per-batch spatial bucket sort of lines (64 Morton cells, midpoint key).
// Processing order only — outputs land at original rows (numerics identical).
// ---------------------------------------------------------------------------
__global__ __launch_bounds__(1024) void k_order(const float* __restrict__ lines,
                                                int* __restrict__ perm) {
  __shared__ int hist[64];
  __shared__ int off[64];
  const int b = blockIdx.x;
  const int t = threadIdx.x;
  if (t < 64) hist[t] = 0;
  __syncthreads();
  int mycell[5];
  #pragma unroll
  for (int i = 0; i < 5; i++) {
    const int l = t * 5 + i;
    int cell = -1;
    if (l < L_) {
      const float* ln = lines + (size_t)(b * L_ + l) * 4;
      float mx = 0.5f * (ln[0] + ln[2]);
      float my = 0.5f * (ln[1] + ln[3]);
      int cx = min(max((int)mx, 0), 255) >> 5;   // 0..7
      int cy = min(max((int)my, 0), 255) >> 5;   // 0..7
      cell = (cx & 1) | ((cy & 1) << 1) | ((cx & 2) << 1) | ((cy & 2) << 2)
           | ((cx & 4) << 2) | ((cy & 4) << 3);
      atomicAdd(&hist[cell], 1);
    }
    mycell[i] = cell;
  }
  __syncthreads();
  if (t == 0) {
    int s = 0;
    for (int c = 0; c < 64; c++) { off[c] = s; s += hist[c]; }
  }
  __syncthreads();
  #pragma unroll
  for (int i = 0; i < 5; i++) {
    if (mycell[i] >= 0) {
      int slot = atomicAdd(&off[mycell[i]], 1);
      perm[b * L_ + slot] = t * 5 + i;
    }
  }
}

// ---------------------------------------------------------------------------
// K1: conv as split-f16 MFMA GEMM.  M=262144 pixels, N=128, K=256.
// (unchanged — memory-bound, near its ~67 us floor)
// ---------------------------------------------------------------------------
__global__ __launch_bounds__(256) void k_conv_mfma(const float* __restrict__ fin,
                                                   const f16* __restrict__ wh,
                                                   const f16* __restrict__ wl,
                                                   const float* __restrict__ bias,
                                                   float* __restrict__ xout) {
  __shared__ f16 lds[16384];  // elems: Ah@0  Al@4096  Bh@8192  Bl@12288
  const int t = threadIdx.x;
  const int P0 = blockIdx.x * 128;
  const int b  = P0 >> 16;
  const int ph0 = P0 & 65535;
  const int lane = t & 63, wave = t >> 6;
  const int quad = lane >> 4, lo = lane & 15;
  const int wm = wave >> 1, wn = wave & 1;

  const int c_base = (t & 7) * 4;
  const int p = (t >> 3) * 4;
  const size_t fbase = (size_t)b * CIN_ * HW_ + (size_t)ph0 + p;

  const int srow = t >> 2;
  const int skb  = (t & 3) * 16;
  const char* gBh = (const char*)wh + (size_t)srow * 512 + skb;
  const char* gBl = (const char*)wl + (size_t)srow * 512 + skb;
  char* ldsB = (char*)lds + t * 16;

  f32x4 acc[4][4];
  #pragma unroll
  for (int mt = 0; mt < 4; mt++)
    #pragma unroll
    for (int nt = 0; nt < 4; nt++) acc[mt][nt] = (f32x4){0.f, 0.f, 0.f, 0.f};

  float4 av[4], nv[4];
  #pragma unroll
  for (int j = 0; j < 4; j++)
    av[j] = *(const float4*)(fin + fbase + (size_t)(c_base + j) * HW_);

  for (int kc = 0; kc < 8; kc++) {
    const size_t bko = (size_t)kc * 64;
    gload16(gBh + bko,         ldsB + 16384);
    gload16(gBh + 32768 + bko, ldsB + 16384 + 4096);
    gload16(gBl + bko,         ldsB + 24576);
    gload16(gBl + 32768 + bko, ldsB + 24576 + 4096);

    #pragma unroll
    for (int i = 0; i < 4; i++) {
      f16 hh[4], ll[4];
      #pragma unroll
      for (int j = 0; j < 4; j++) {
        float v = ((const float*)&av[j])[i];
        hh[j] = (f16)v;
        ll[j] = (f16)(v - (float)hh[j]);
      }
      *(f16x4*)(&lds[(p + i) * 32 + c_base])        = (f16x4){hh[0], hh[1], hh[2], hh[3]};
      *(f16x4*)(&lds[4096 + (p + i) * 32 + c_base]) = (f16x4){ll[0], ll[1], ll[2], ll[3]};
    }
    __syncthreads();

    if (kc < 7) {
      #pragma unroll
      for (int j = 0; j < 4; j++)
        nv[j] = *(const float4*)(fin + fbase + (size_t)((kc + 1) * 32 + c_base + j) * HW_);
    }

    f16x8 ah[4], al[4], bh4[4], bl4[4];
    #pragma unroll
    for (int mt = 0; mt < 4; mt++) {
      int row = wm * 64 + mt * 16 + lo;
      ah[mt] = *(const f16x8*)(&lds[row * 32 + quad * 8]);
      al[mt] = *(const f16x8*)(&lds[4096 + row * 32 + quad * 8]);
    }
    #pragma unroll
    for (int nt = 0; nt < 4; nt++) {
      int row = wn * 64 + nt * 16 + lo;
      bh4[nt] = *(const f16x8*)(&lds[8192 + row * 32 + quad * 8]);
      bl4[nt] = *(const f16x8*)(&lds[12288 + row * 32 + quad * 8]);
    }
    #pragma unroll
    for (int mt = 0; mt < 4; mt++)
      #pragma unroll
      for (int nt = 0; nt < 4; nt++) {
        acc[mt][nt] = __builtin_amdgcn_mfma_f32_16x16x32_f16(ah[mt], bh4[nt], acc[mt][nt], 0, 0, 0);
        acc[mt][nt] = __builtin_amdgcn_mfma_f32_16x16x32_f16(ah[mt], bl4[nt], acc[mt][nt], 0, 0, 0);
        acc[mt][nt] = __builtin_amdgcn_mfma_f32_16x16x32_f16(al[mt], bh4[nt], acc[mt][nt], 0, 0, 0);
      }
    __syncthreads();
    #pragma unroll
    for (int j = 0; j < 4; j++) av[j] = nv[j];
  }

  #pragma unroll
  for (int nt = 0; nt < 4; nt++) {
    int col = wn * 64 + nt * 16 + lo;
    float bv = bias[col];
    #pragma unroll
    for (int mt = 0; mt < 4; mt++) {
      int rowb = P0 + wm * 64 + mt * 16 + quad * 4;
      #pragma unroll
      for (int r = 0; r < 4; r++)
        xout[(size_t)(rowb + r) * DLOI_ + col] = acc[mt][nt][r] + bv;
    }
  }
}

// ---------------------------------------------------------------------------
// K2: sample 32 pts/line, bilinear, maxpool by 4 -> feat as f16 hi/lo planes
// (geometry precompute + sorted processing order; unchanged)
// ---------------------------------------------------------------------------
__global__ __launch_bounds__(128) void k_sample(const float* __restrict__ x,
                                                const float* __restrict__ lines,
                                                const int* __restrict__ perm,
                                                f16* __restrict__ fh,
                                                f16* __restrict__ fl) {
  __shared__ int4   s_off[NPTS0_];
  __shared__ float4 s_wt [NPTS0_];
  const int blk0 = blockIdx.x;
  const int s = (blk0 & 7) * (M_ / 8) + (blk0 >> 3);
  const int b = s / L_;
  const int row = b * L_ + perm[s];       // original line row
  const int c = threadIdx.x;
  const float* ln = lines + (size_t)row * 4;

  if (c < NPTS0_) {
    const float e0x = ln[0], e0y = ln[1], e1x = ln[2], e1y = ln[3];
    const int i = c;
    float lam = (float)i * (1.0f / 31.0f);
    float px = e0x * lam + e1x * (1.f - lam) - 0.5f;
    float py = e0y * lam + e1y * (1.f - lam) - 0.5f;
    float px0 = fminf(fmaxf(floorf(px), 0.f), 255.f);
    float py0 = fminf(fmaxf(floorf(py), 0.f), 255.f);
    float px1 = fminf(px0 + 1.f, 255.f);
    float py1 = fminf(py0 + 1.f, 255.f);
    int ix0 = (int)px0, iy0 = (int)py0, ix1 = (int)px1, iy1 = (int)py1;
    s_wt[i]  = make_float4((px1 - px) * (py1 - py),   // w00
                           (px - px0) * (py1 - py),   // w10
                           (px1 - px) * (py - py0),   // w01
                           (px - px0) * (py - py0));  // w11
    s_off[i] = make_int4((ix0 * W_ + iy0) * (DLOI_ * 4),
                         (ix1 * W_ + iy0) * (DLOI_ * 4),
                         (ix0 * W_ + iy1) * (DLOI_ * 4),
                         (ix1 * W_ + iy1) * (DLOI_ * 4));
  }
  __syncthreads();

  const char* xbc = (const char*)(x + (size_t)b * HW_ * DLOI_) + c * 4;
  f16x8 vh, vl;
  for (int q = 0; q < NPTS1_; q++) {
    float m = -1e30f;
    #pragma unroll
    for (int r = 0; r < 4; r++) {
      const int i = q * 4 + r;
      const int4   o = s_off[i];
      const float4 w = s_wt[i];
      float v = w.x * *(const float*)(xbc + o.x)
              + w.y * *(const float*)(xbc + o.y)
              + w.z * *(const float*)(xbc + o.z)
              + w.w * *(const float*)(xbc + o.w);
      m = fmaxf(m, v);
    }
    f16 h = (f16)m;
    vh[q] = h;
    vl[q] = (f16)(m - (float)h);
  }
  *(f16x8*)(fh + (size_t)row * DFC_ + c * 8) = vh;
  *(f16x8*)(fl + (size_t)row * DFC_ + c * 8) = vl;
}

// ---------------------------------------------------------------------------
// K-tsplit: W[K][N] fp32 -> transposed f16 hi/lo planes Wt[N][K]
// ---------------------------------------------------------------------------
__global__ __launch_bounds__(256) void k_tsplit(const float* __restrict__ Wsrc,
                                                f16* __restrict__ Th,
                                                f16* __restrict__ Tl) {
  __shared__ float tile[32][33];
  const int bj = blockIdx.x, bi = blockIdx.y;
  const int tx = threadIdx.x & 31, ty = threadIdx.x >> 5;
  #pragma unroll
  for (int r = ty; r < 32; r += 8)
    tile[r][tx] = Wsrc[(size_t)(bi * 32 + r) * 1024 + bj * 32 + tx];
  __syncthreads();
  #pragma unroll
  for (int r = ty; r < 32; r += 8) {
    float v = tile[tx][r];
    f16 h = (f16)v;
    size_t o = (size_t)(bj * 32 + r) * 1024 + bi * 32 + tx;
    Th[o] = h;
    Tl[o] = (f16)(v - (float)h);
  }
}

// ---------------------------------------------------------------------------
// K3/K4: split-f16 3-product MFMA GEMM — round-7: 2-wave / 128x64-per-wave.
//
// Round-6 post-mortem: 4-wave 2Mx2N had 2x LDS-read redundancy on A and B
// (64 KB read per 32 KB tile) — LDS-read-bound at ~36% MfmaUtil.  This round
// keeps EVERYTHING structural (128x128 block tile, 32 KB slots, 2-slot ring,
// 2 blocks/CU, same swizzle pair, same vmcnt(0)+barrier per tile, same
// hh,lh,hl accumulation order -> bit-identical numerics) but decomposes as
// 2 waves (1M x 2N), per-wave output 128x64 (acc[8][4]):
//   A read once per wave (2x total), B read once per block -> 48 KB reads
//   per block-tile (-25%), FLOP/LDS-byte 48 -> 64, 96 MFMAs per wave-tile.
// A-fragments are read mt-major (once each, 12 MFMAs per pair) to bound
// register liveness (~200 VGPR, no spill).
// ---------------------------------------------------------------------------
#define BKT_    32
#define NTT_    (DFC_/BKT_)   // 32 K-tiles
#define SLOT_B_ 32768         // bytes per slot
#define AH_O_   0
#define AL_O_   8192
#define BH_O_   16384
#define BL_O_   24576

template <bool SPLIT_OUT>
__global__ __launch_bounds__(128, 1) void k_gemm_f16x3(
    const f16* __restrict__ Ah, const f16* __restrict__ Al,
    const f16* __restrict__ Bh, const f16* __restrict__ Bl,
    const float* __restrict__ bias,
    f16* __restrict__ Oh, f16* __restrict__ Ol,
    const float* __restrict__ w3, float* __restrict__ part) {
  __shared__ f16 lds[2 * SLOT_B_ / 2];   // 64 KB -> 2 blocks/CU
  char* ldsc = (char*)lds;

  // XCD swizzle: nwg = 1256 = 8*157 exactly -> bijective remap; all 8 nb of
  // a band land on one XCD (A-band L2 reuse).
  const int orig = blockIdx.x;
  const int wg = (orig & 7) * 157 + (orig >> 3);
  const int band = wg >> 3;     // 0..156
  const int nb   = wg & 7;      // 0..7
  const int r0 = band * 128;
  const int n0 = nb * 128;

  const int t = threadIdx.x;            // 0..127
  const int lane = t & 63, wave = t >> 6;   // 2 waves
  const int quad = lane >> 4, lo = lane & 15;

  // --- staging: each plane = 8 KB = 512 x 16B chunks; 128 threads x 4 passes.
  // Inverse-swizzled global source chunk (involution u^((u>>3)&7)) + linear
  // gload_lds dest + swizzled ds_read (rule #21 both-sides).
  size_t ssrc[4]; int sdst[4];
  #pragma unroll
  for (int pp = 0; pp < 4; pp++) {
    const uint32_t u = (uint32_t)(pp * 128 + t);
    const uint32_t us = u ^ ((u >> 3) & 7);
    ssrc[pp] = (size_t)(us >> 2) * 2048 + (size_t)(us & 3) * 16;
    sdst[pp] = pp * 2048 + t * 16;
  }

  const char* gAh = (const char*)Ah + (size_t)r0 * 2048;
  const char* gAl = (const char*)Al + (size_t)r0 * 2048;
  const char* gBh = (const char*)Bh + (size_t)n0 * 2048;
  const char* gBl = (const char*)Bl + (size_t)n0 * 2048;

  // --- swizzled ds_read byte offsets within each 8 KB plane
  int roffA[8], roffB[4];
  #pragma unroll
  for (int mt = 0; mt < 8; mt++) {
    int r = mt * 16 + lo;                       // wave covers all 128 A-rows
    roffA[mt] = (((r * 4 + quad) ^ ((r >> 1) & 7)) << 4);
  }
  #pragma unroll
  for (int nt = 0; nt < 4; nt++) {
    int r = wave * 64 + nt * 16 + lo;           // wave's 64-col B half
    roffB[nt] = (((r * 4 + quad) ^ ((r >> 1) & 7)) << 4);
  }

  f32x4 acc[8][4];
  #pragma unroll
  for (int mt = 0; mt < 8; mt++)
    #pragma unroll
    for (int nt = 0; nt < 4; nt++) acc[mt][nt] = (f32x4){0.f, 0.f, 0.f, 0.f};

  // --- prologue: stage tile 0 -> slot 0 (16 loads/thread)
  #pragma unroll
  for (int pp = 0; pp < 4; pp++) {
    gload16(gAh + ssrc[pp], ldsc + AH_O_ + sdst[pp]);
    gload16(gAl + ssrc[pp], ldsc + AL_O_ + sdst[pp]);
    gload16(gBh + ssrc[pp], ldsc + BH_O_ + sdst[pp]);
    gload16(gBl + ssrc[pp], ldsc + BL_O_ + sdst[pp]);
  }
  asm volatile("s_waitcnt vmcnt(0)" ::: "memory");
  __builtin_amdgcn_s_barrier();

  for (int tt = 0; tt < NTT_; ++tt) {
    const char* sc = ldsc + (tt & 1) * SLOT_B_;
    char* sw = ldsc + ((tt + 1) & 1) * SLOT_B_;
    const size_t go = (size_t)(tt + 1) * 64;   // k-byte offset of tile tt+1
    const bool pf = (tt + 1 < NTT_);

    // 1. issue next-tile staging first (slot^1 fully consumed at tt-1)
    if (pf) {
      #pragma unroll
      for (int pp = 0; pp < 4; pp++) {
        gload16(gAh + go + ssrc[pp], sw + AH_O_ + sdst[pp]);
        gload16(gAl + go + ssrc[pp], sw + AL_O_ + sdst[pp]);
        gload16(gBh + go + ssrc[pp], sw + BH_O_ + sdst[pp]);
        gload16(gBl + go + ssrc[pp], sw + BL_O_ + sdst[pp]);
      }
    }

    // 2. B fragments once per tile (32 VGPRs live across the tile)
    f16x8 bh[4], bl[4];
    #pragma unroll
    for (int nt = 0; nt < 4; nt++)
      bh[nt] = *(const f16x8*)(sc + BH_O_ + roffB[nt]);
    #pragma unroll
    for (int nt = 0; nt < 4; nt++)
      bl[nt] = *(const f16x8*)(sc + BL_O_ + roffB[nt]);

    // 3. mt-major: read each A-fragment pair once, 12 MFMAs per pair.
    //    Product order per acc: hh, lh, hl  -> bit-identical accumulation.
    __builtin_amdgcn_s_setprio(1);
    #pragma unroll
    for (int mt = 0; mt < 8; mt++) {
      f16x8 ah = *(const f16x8*)(sc + AH_O_ + roffA[mt]);
      f16x8 al = *(const f16x8*)(sc + AL_O_ + roffA[mt]);
      #pragma unroll
      for (int nt = 0; nt < 4; nt++)
        acc[mt][nt] = __builtin_amdgcn_mfma_f32_16x16x32_f16(ah, bh[nt], acc[mt][nt], 0, 0, 0);
      #pragma unroll
      for (int nt = 0; nt < 4; nt++)
        acc[mt][nt] = __builtin_amdgcn_mfma_f32_16x16x32_f16(al, bh[nt], acc[mt][nt], 0, 0, 0);
      #pragma unroll
      for (int nt = 0; nt < 4; nt++)
        acc[mt][nt] = __builtin_amdgcn_mfma_f32_16x16x32_f16(ah, bl[nt], acc[mt][nt], 0, 0, 0);
    }
    __builtin_amdgcn_s_setprio(0);

    // 4. tile boundary: next tile landed.  Drain hidden by co-resident block.
    if (pf) asm volatile("s_waitcnt vmcnt(0)" ::: "memory");
    __builtin_amdgcn_s_barrier();
  }
  // loop ends with a barrier -> LDS free for epilogue staging

  if (SPLIT_OUT) {
    // wave-private 32 KB (2 waves x 32 KB = 64 KB): hi plane @0 (128 rows x
    // 128 B), lo @16384.  16B-chunk XOR swizzle, then full-line f16x8 stores.
    char* ep = ldsc + wave * 32768;
    #pragma unroll
    for (int mt = 0; mt < 8; mt++)
      #pragma unroll
      for (int nt = 0; nt < 4; nt++) {
        const int col = n0 + wave * 64 + nt * 16 + lo;
        const float bv = bias[col];
        const int col_l = nt * 16 + lo;
        #pragma unroll
        for (int r = 0; r < 4; r++) {
          const int rl = mt * 16 + quad * 4 + r;
          float v = fmaxf(acc[mt][nt][r] + bv, 0.f);
          f16 h = (f16)v;
          f16 lw = (f16)(v - (float)h);
          const int byte = rl * 128 + ((((col_l >> 3) ^ (rl & 7)) << 4)) + (col_l & 7) * 2;
          *(f16*)(ep + byte) = h;
          *(f16*)(ep + 16384 + byte) = lw;
        }
      }
    asm volatile("s_waitcnt lgkmcnt(0)" ::: "memory");  // wave-internal
    __builtin_amdgcn_sched_barrier(0);
    const int r8 = lane >> 3;   // row within 8-row group
    const int ck = lane & 7;    // 16B chunk within row
    #pragma unroll
    for (int g = 0; g < 16; g++) {
      const int rl = g * 8 + r8;
      const int grow = r0 + rl;
      const int swz = ((ck ^ (rl & 7)) << 4);
      f16x8 vh = *(const f16x8*)(ep + rl * 128 + swz);
      f16x8 vl = *(const f16x8*)(ep + 16384 + rl * 128 + swz);
      if (grow < M_) {
        const size_t gb = (size_t)grow * 2048 + (size_t)(n0 + wave * 64) * 2 + ck * 16;
        *(f16x8*)((char*)Oh + gb) = vh;
        *(f16x8*)((char*)Ol + gb) = vl;
      }
    }
  } else {
    // fused head: p[r][j] = sum over this wave's 64 cols of relu(h2)*w3
    const int slot = nb * 2 + wave;   // 16 slots per row
    #pragma unroll
    for (int mt = 0; mt < 8; mt++) {
      float p[4][4];
      #pragma unroll
      for (int r = 0; r < 4; r++)
        #pragma unroll
        for (int j = 0; j < 4; j++) p[r][j] = 0.f;
      #pragma unroll
      for (int nt = 0; nt < 4; nt++) {
        const int col = n0 + wave * 64 + nt * 16 + lo;
        const float bv = bias[col];
        float4 wv = *(const float4*)(w3 + col * 4);
        #pragma unroll
        for (int r = 0; r < 4; r++) {
          float v = fmaxf(acc[mt][nt][r] + bv, 0.f);
          p[r][0] = fmaf(v, wv.x, p[r][0]);
          p[r][1] = fmaf(v, wv.y, p[r][1]);
          p[r][2] = fmaf(v, wv.z, p[r][2]);
          p[r][3] = fmaf(v, wv.w, p[r][3]);
        }
      }
      // reduce over the 16 lo-lanes (stays within the quad group)
      #pragma unroll
      for (int r = 0; r < 4; r++)
        #pragma unroll
        for (int j = 0; j < 4; j++) {
          p[r][j] += __shfl_xor(p[r][j], 1);
          p[r][j] += __shfl_xor(p[r][j], 2);
          p[r][j] += __shfl_xor(p[r][j], 4);
          p[r][j] += __shfl_xor(p[r][j], 8);
        }
      if (lo == 0) {
        const int rowb = r0 + mt * 16 + quad * 4;
        #pragma unroll
        for (int r = 0; r < 4; r++)
          *(float4*)(part + ((size_t)slot * MPAD_ + rowb + r) * 4) =
              make_float4(p[r][0], p[r][1], p[r][2], p[r][3]);
      }
    }
  }
}

// ---------------------------------------------------------------------------
// K5: sum 16 logit partials + b3, softmax, keep/argmax key.  1 thread/row.
// ---------------------------------------------------------------------------
__global__ __launch_bounds__(256) void k_head2(const float* __restrict__ part,
                                               const float* __restrict__ b3,
                                               float* __restrict__ s_out,
                                               int* __restrict__ key_out) {
  const int row = blockIdx.x * 256 + threadIdx.x;
  if (row >= M_) return;
  float l0 = b3[0], l1 = b3[1], l2 = b3[2], l3 = b3[3];
  #pragma unroll
  for (int sl = 0; sl < 16; sl++) {
    float4 p = *(const float4*)(part + ((size_t)sl * MPAD_ + row) * 4);
    l0 += p.x; l1 += p.y; l2 += p.z; l3 += p.w;
  }
  float mx = fmaxf(fmaxf(l0, l1), fmaxf(l2, l3));
  float e0 = expf(l0 - mx), e1 = expf(l1 - mx), e2 = expf(l2 - mx), e3 = expf(l3 - mx);
  float inv = 1.f / (e0 + e1 + e2 + e3);
  float s0 = e0 * inv, s1 = e1 * inv, s2 = e2 * inv, s3 = e3 * inv;
  *(float4*)(s_out + (size_t)row * 4) = make_float4(s0, s1, s2, s3);
  bool keep = ((s1 > 0.25f) || (s2 > 0.25f) || (s3 > 0.25f)) && (s0 < 0.25f);
  int am = 0; float best = s0;
  if (s1 > best) { best = s1; am = 1; }
  if (s2 > best) { best = s2; am = 2; }
  if (s3 > best) { best = s3; am = 3; }
  key_out[row] = keep ? am : -1;
}

// ---------------------------------------------------------------------------
// K6: per-batch stable counting sort (5 classes) + cyclic select.
// ---------------------------------------------------------------------------
__global__ __launch_bounds__(1024) void k_select(const int* __restrict__ key,
                                                 const float* __restrict__ lines,
                                                 const float* __restrict__ s,
                                                 float* __restrict__ out_lines,
                                                 float* __restrict__ out_score) {
  __shared__ int s_ord[L_];
  __shared__ int s_scan[1024];
  __shared__ int s_tot[5];
  const int b = blockIdx.x;
  const int t = threadIdx.x;
  const int base_l = t * 5;
  int cls[5];
  int c[5] = {0, 0, 0, 0, 0};
  #pragma unroll
  for (int i = 0; i < 5; i++) {
    int l = base_l + i;
    int cl = -1;
    if (l < L_) {
      int k = key[b * L_ + l];
      cl = (k < 0) ? 4 : (3 - k);
      c[cl]++;
    }
    cls[i] = cl;
  }
  int pf[5];
  for (int cc = 0; cc < 5; cc++) {
    s_scan[t] = c[cc];
    __syncthreads();
    for (int off = 1; off < 1024; off <<= 1) {
      int add = (t >= off) ? s_scan[t - off] : 0;
      __syncthreads();
      s_scan[t] += add;
      __syncthreads();
    }
    pf[cc] = s_scan[t] - c[cc];
    if (t == 1023) s_tot[cc] = s_scan[1023];
    __syncthreads();
  }
  int basec[5];
  basec[0] = 0;
  #pragma unroll
  for (int cc = 1; cc < 5; cc++) basec[cc] = basec[cc - 1] + s_tot[cc - 1];
  int run[5] = {0, 0, 0, 0, 0};
  #pragma unroll
  for (int i = 0; i < 5; i++) {
    if (cls[i] >= 0) {
      int cl = cls[i];
      int pos = basec[cl] + pf[cl] + run[cl];
      run[cl]++;
      s_ord[pos] = base_l + i;
    }
  }
  const int cnt = L_ - s_tot[4];
  __syncthreads();
  for (int j = t; j < NOUT_; j += 1024) {
    float4 lv = make_float4(0.f, 0.f, 0.f, 0.f);
    float4 sv = make_float4(0.f, 0.f, 0.f, 0.f);
    if (cnt > 0) {
      int idx = s_ord[j % cnt];
      lv = *(const float4*)(lines + (size_t)(b * L_ + idx) * 4);
      sv = *(const float4*)(s + (size_t)(b * L_ + idx) * 4);
    }
    *(float4*)(out_lines + (size_t)(b * NOUT_ + j) * 4) = lv;
    *(float4*)(out_score + (size_t)(b * NOUT_ + j) * 4) = sv;
  }
}

// ---------------------------------------------------------------------------
extern "C" void kernel_launch(void* const* d_in, const int* in_sizes, int n_in,
                              void* d_out, int out_size, void* d_ws, size_t ws_size,
                              hipStream_t stream) {
  const float* feature = (const float*)d_in[0];
  const float* lines   = (const float*)d_in[1];
  const float* fc1_w   = (const float*)d_in[2];
  const float* fc1_b   = (const float*)d_in[3];
  const float* w1      = (const float*)d_in[4];
  const float* b1      = (const float*)d_in[5];
  const float* w2      = (const float*)d_in[6];
  const float* b2      = (const float*)d_in[7];
  const float* w3      = (const float*)d_in[8];
  const float* b3      = (const float*)d_in[9];

  float* out_lines = (float*)d_out;
  float* out_score = out_lines + B_ * NOUT_ * 4;
  float* s_out     = out_score + B_ * NOUT_ * 4;

  // workspace layout (bytes): see prior rounds (unchanged).
  char* ws = (char*)d_ws;
  float* x    = (float*)(ws);
  f16*   h1h  = (f16*)(ws);
  f16*   h1l  = (f16*)(ws + 41156608ull);
  float* part = (float*)(ws + 82313216ull);
  f16*   fh   = (f16*)(ws + 134217728ull);
  f16*   fl   = (f16*)(ws + 134217728ull + 41156608ull);
  f16*   wt1h = (f16*)(ws + 216530944ull);
  f16*   wt1l = (f16*)(ws + 216530944ull + 2097152ull);
  f16*   wt2h = (f16*)(ws + 216530944ull + 2ull * 2097152ull);
  f16*   wt2l = (f16*)(ws + 216530944ull + 3ull * 2097152ull);
  int*   keys = (int*)(ws + 224919552ull);
  f16*   wc_h = (f16*)(ws + 224999552ull);
  f16*   wc_l = (f16*)(ws + 224999552ull + 65536ull);

  k_order<<<dim3(B_), 1024, 0, stream>>>(lines, keys);   // perm in keys buf
  k_wsplit<<<dim3(32), 256, 0, stream>>>(fc1_w, wc_h, wc_l);
  k_tsplit<<<dim3(32, 32), 256, 0, stream>>>(w1, wt1h, wt1l);
  k_tsplit<<<dim3(32, 32), 256, 0, stream>>>(w2, wt2h, wt2l);
  k_conv_mfma<<<dim3((B_ * HW_) / 128), 256, 0, stream>>>(feature, wc_h, wc_l, fc1_b, x);
  k_sample<<<dim3(M_), 128, 0, stream>>>(x, lines, keys, fh, fl);
  k_gemm_f16x3<true><<<dim3(1256), 128, 0, stream>>>(
      fh, fl, wt1h, wt1l, b1, h1h, h1l, nullptr, nullptr);
  k_gemm_f16x3<false><<<dim3(1256), 128, 0, stream>>>(
      h1h, h1l, wt2h, wt2l, b2, nullptr, nullptr, w3, part);
  k_head2<<<dim3((M_ + 255) / 256), 256, 0, stream>>>(part, b3, s_out, keys);
  k_select<<<dim3(B_), 1024, 0, stream>>>(keys, lines, s_out, out_lines, out_score);
}

// Round 8
// 820.635 us; speedup vs baseline: 1.0916x; 1.0916x over previous
//
#include <hip/hip_runtime.h>
#include <cstdint>
#include <cstddef>

#define B_     4
#define L_     5000
#define H_     256
#define W_     256
#define HW_    65536
#define CIN_   256
#define DLOI_  128
#define NPTS0_ 32
#define NPTS1_ 8
#define DFC_   1024
#define NOUT_  2500
#define M_     (B_*L_)   // 20000
#define MPAD_  20096     // 157 * 128
#define NBAND_ 157       // MPAD_/128

typedef _Float16 f16;
typedef _Float16 f16x4 __attribute__((ext_vector_type(4)));
typedef _Float16 f16x8 __attribute__((ext_vector_type(8)));
typedef float    f32x4 __attribute__((ext_vector_type(4)));

__device__ __forceinline__ void gload16(const void* g, void* l) {
  __builtin_amdgcn_global_load_lds(
      (const __attribute__((address_space(1))) void*)g,
      (__attribute__((address_space(3))) void*)l, 16, 0, 0);
}

// ---------------------------------------------------------------------------
// K0a: split fc1_w [128][256] fp32 -> f16 hi/lo planes (same [n][k] layout)
// ---------------------------------------------------------------------------
__global__ __launch_bounds__(256) void k_wsplit(const float* __restrict__ src,
                                                f16* __restrict__ h,
                                                f16* __restrict__ l) {
  int i = (blockIdx.x * 256 + threadIdx.x) * 4;
  float4 v = *(const float4*)(src + i);
  f16 h0 = (f16)v.x, h1 = (f16)v.y, h2 = (f16)v.z, h3 = (f16)v.w;
  *(f16x4*)(h + i) = (f16x4){h0, h1, h2, h3};
  *(f16x4*)(l + i) = (f16x4){(f16)(v.x - (float)h0), (f16)(v.y - (float)h1),
                             (f16)(v.z - (float)h2), (f16)(v.w - (float)h3)};
}

// ---------------------------------------------------------------------------
// K0b: per-batch spatial bucket sort of lines (64 Morton cells, midpoint key).
// Processing order only — outputs land at original rows (numerics identical).
// ---------------------------------------------------------------------------
__global__ __launch_bounds__(1024) void k_order(const float* __restrict__ lines,
                                                int* __restrict__ perm) {
  __shared__ int hist[64];
  __shared__ int off[64];
  const int b = blockIdx.x;
  const int t = threadIdx.x;
  if (t < 64) hist[t] = 0;
  __syncthreads();
  int mycell[5];
  #pragma unroll
  for (int i = 0; i < 5; i++) {
    const int l = t * 5 + i;
    int cell = -1;
    if (l < L_) {
      const float* ln = lines + (size_t)(b * L_ + l) * 4;
      float mx = 0.5f * (ln[0] + ln[2]);
      float my = 0.5f * (ln[1] + ln[3]);
      int cx = min(max((int)mx, 0), 255) >> 5;   // 0..7
      int cy = min(max((int)my, 0), 255) >> 5;   // 0..7
      cell = (cx & 1) | ((cy & 1) << 1) | ((cx & 2) << 1) | ((cy & 2) << 2)
           | ((cx & 4) << 2) | ((cy & 4) << 3);
      atomicAdd(&hist[cell], 1);
    }
    mycell[i] = cell;
  }
  __syncthreads();
  if (t == 0) {
    int s = 0;
    for (int c = 0; c < 64; c++) { off[c] = s; s += hist[c]; }
  }
  __syncthreads();
  #pragma unroll
  for (int i = 0; i < 5; i++) {
    if (mycell[i] >= 0) {
      int slot = atomicAdd(&off[mycell[i]], 1);
      perm[b * L_ + slot] = t * 5 + i;
    }
  }
}

// ---------------------------------------------------------------------------
// K1: conv as split-f16 MFMA GEMM.  M=262144 pixels, N=128, K=256.
// (unchanged — memory-bound, near its ~67 us floor)
// ---------------------------------------------------------------------------
__global__ __launch_bounds__(256) void k_conv_mfma(const float* __restrict__ fin,
                                                   const f16* __restrict__ wh,
                                                   const f16* __restrict__ wl,
                                                   const float* __restrict__ bias,
                                                   float* __restrict__ xout) {
  __shared__ f16 lds[16384];  // elems: Ah@0  Al@4096  Bh@8192  Bl@12288
  const int t = threadIdx.x;
  const int P0 = blockIdx.x * 128;
  const int b  = P0 >> 16;
  const int ph0 = P0 & 65535;
  const int lane = t & 63, wave = t >> 6;
  const int quad = lane >> 4, lo = lane & 15;
  const int wm = wave >> 1, wn = wave & 1;

  const int c_base = (t & 7) * 4;
  const int p = (t >> 3) * 4;
  const size_t fbase = (size_t)b * CIN_ * HW_ + (size_t)ph0 + p;

  const int srow = t >> 2;
  const int skb  = (t & 3) * 16;
  const char* gBh = (const char*)wh + (size_t)srow * 512 + skb;
  const char* gBl = (const char*)wl + (size_t)srow * 512 + skb;
  char* ldsB = (char*)lds + t * 16;

  f32x4 acc[4][4];
  #pragma unroll
  for (int mt = 0; mt < 4; mt++)
    #pragma unroll
    for (int nt = 0; nt < 4; nt++) acc[mt][nt] = (f32x4){0.f, 0.f, 0.f, 0.f};

  float4 av[4], nv[4];
  #pragma unroll
  for (int j = 0; j < 4; j++)
    av[j] = *(const float4*)(fin + fbase + (size_t)(c_base + j) * HW_);

  for (int kc = 0; kc < 8; kc++) {
    const size_t bko = (size_t)kc * 64;
    gload16(gBh + bko,         ldsB + 16384);
    gload16(gBh + 32768 + bko, ldsB + 16384 + 4096);
    gload16(gBl + bko,         ldsB + 24576);
    gload16(gBl + 32768 + bko, ldsB + 24576 + 4096);

    #pragma unroll
    for (int i = 0; i < 4; i++) {
      f16 hh[4], ll[4];
      #pragma unroll
      for (int j = 0; j < 4; j++) {
        float v = ((const float*)&av[j])[i];
        hh[j] = (f16)v;
        ll[j] = (f16)(v - (float)hh[j]);
      }
      *(f16x4*)(&lds[(p + i) * 32 + c_base])        = (f16x4){hh[0], hh[1], hh[2], hh[3]};
      *(f16x4*)(&lds[4096 + (p + i) * 32 + c_base]) = (f16x4){ll[0], ll[1], ll[2], ll[3]};
    }
    __syncthreads();

    if (kc < 7) {
      #pragma unroll
      for (int j = 0; j < 4; j++)
        nv[j] = *(const float4*)(fin + fbase + (size_t)((kc + 1) * 32 + c_base + j) * HW_);
    }

    f16x8 ah[4], al[4], bh4[4], bl4[4];
    #pragma unroll
    for (int mt = 0; mt < 4; mt++) {
      int row = wm * 64 + mt * 16 + lo;
      ah[mt] = *(const f16x8*)(&lds[row * 32 + quad * 8]);
      al[mt] = *(const f16x8*)(&lds[4096 + row * 32 + quad * 8]);
    }
    #pragma unroll
    for (int nt = 0; nt < 4; nt++) {
      int row = wn * 64 + nt * 16 + lo;
      bh4[nt] = *(const f16x8*)(&lds[8192 + row * 32 + quad * 8]);
      bl4[nt] = *(const f16x8*)(&lds[12288 + row * 32 + quad * 8]);
    }
    #pragma unroll
    for (int mt = 0; mt < 4; mt++)
      #pragma unroll
      for (int nt = 0; nt < 4; nt++) {
        acc[mt][nt] = __builtin_amdgcn_mfma_f32_16x16x32_f16(ah[mt], bh4[nt], acc[mt][nt], 0, 0, 0);
        acc[mt][nt] = __builtin_amdgcn_mfma_f32_16x16x32_f16(ah[mt], bl4[nt], acc[mt][nt], 0, 0, 0);
        acc[mt][nt] = __builtin_amdgcn_mfma_f32_16x16x32_f16(al[mt], bh4[nt], acc[mt][nt], 0, 0, 0);
      }
    __syncthreads();
    #pragma unroll
    for (int j = 0; j < 4; j++) av[j] = nv[j];
  }

  #pragma unroll
  for (int nt = 0; nt < 4; nt++) {
    int col = wn * 64 + nt * 16 + lo;
    float bv = bias[col];
    #pragma unroll
    for (int mt = 0; mt < 4; mt++) {
      int rowb = P0 + wm * 64 + mt * 16 + quad * 4;
      #pragma unroll
      for (int r = 0; r < 4; r++)
        xout[(size_t)(rowb + r) * DLOI_ + col] = acc[mt][nt][r] + bv;
    }
  }
}

// ---------------------------------------------------------------------------
// K2: sample 32 pts/line, bilinear, maxpool by 4 -> feat as f16 hi/lo planes
// (geometry precompute + sorted processing order; unchanged)
// ---------------------------------------------------------------------------
__global__ __launch_bounds__(128) void k_sample(const float* __restrict__ x,
                                                const float* __restrict__ lines,
                                                const int* __restrict__ perm,
                                                f16* __restrict__ fh,
                                                f16* __restrict__ fl) {
  __shared__ int4   s_off[NPTS0_];
  __shared__ float4 s_wt [NPTS0_];
  const int blk0 = blockIdx.x;
  const int s = (blk0 & 7) * (M_ / 8) + (blk0 >> 3);
  const int b = s / L_;
  const int row = b * L_ + perm[s];       // original line row
  const int c = threadIdx.x;
  const float* ln = lines + (size_t)row * 4;

  if (c < NPTS0_) {
    const float e0x = ln[0], e0y = ln[1], e1x = ln[2], e1y = ln[3];
    const int i = c;
    float lam = (float)i * (1.0f / 31.0f);
    float px = e0x * lam + e1x * (1.f - lam) - 0.5f;
    float py = e0y * lam + e1y * (1.f - lam) - 0.5f;
    float px0 = fminf(fmaxf(floorf(px), 0.f), 255.f);
    float py0 = fminf(fmaxf(floorf(py), 0.f), 255.f);
    float px1 = fminf(px0 + 1.f, 255.f);
    float py1 = fminf(py0 + 1.f, 255.f);
    int ix0 = (int)px0, iy0 = (int)py0, ix1 = (int)px1, iy1 = (int)py1;
    s_wt[i]  = make_float4((px1 - px) * (py1 - py),   // w00
                           (px - px0) * (py1 - py),   // w10
                           (px1 - px) * (py - py0),   // w01
                           (px - px0) * (py - py0));  // w11
    s_off[i] = make_int4((ix0 * W_ + iy0) * (DLOI_ * 4),
                         (ix1 * W_ + iy0) * (DLOI_ * 4),
                         (ix0 * W_ + iy1) * (DLOI_ * 4),
                         (ix1 * W_ + iy1) * (DLOI_ * 4));
  }
  __syncthreads();

  const char* xbc = (const char*)(x + (size_t)b * HW_ * DLOI_) + c * 4;
  f16x8 vh, vl;
  for (int q = 0; q < NPTS1_; q++) {
    float m = -1e30f;
    #pragma unroll
    for (int r = 0; r < 4; r++) {
      const int i = q * 4 + r;
      const int4   o = s_off[i];
      const float4 w = s_wt[i];
      float v = w.x * *(const float*)(xbc + o.x)
              + w.y * *(const float*)(xbc + o.y)
              + w.z * *(const float*)(xbc + o.z)
              + w.w * *(const float*)(xbc + o.w);
      m = fmaxf(m, v);
    }
    f16 h = (f16)m;
    vh[q] = h;
    vl[q] = (f16)(m - (float)h);
  }
  *(f16x8*)(fh + (size_t)row * DFC_ + c * 8) = vh;
  *(f16x8*)(fl + (size_t)row * DFC_ + c * 8) = vl;
}

// ---------------------------------------------------------------------------
// K-tsplit: W[K][N] fp32 -> transposed f16 hi/lo planes Wt[N][K]
// ---------------------------------------------------------------------------
__global__ __launch_bounds__(256) void k_tsplit(const float* __restrict__ Wsrc,
                                                f16* __restrict__ Th,
                                                f16* __restrict__ Tl) {
  __shared__ float tile[32][33];
  const int bj = blockIdx.x, bi = blockIdx.y;
  const int tx = threadIdx.x & 31, ty = threadIdx.x >> 5;
  #pragma unroll
  for (int r = ty; r < 32; r += 8)
    tile[r][tx] = Wsrc[(size_t)(bi * 32 + r) * 1024 + bj * 32 + tx];
  __syncthreads();
  #pragma unroll
  for (int r = ty; r < 32; r += 8) {
    float v = tile[tx][r];
    f16 h = (f16)v;
    size_t o = (size_t)(bj * 32 + r) * 1024 + bi * 32 + tx;
    Th[o] = h;
    Tl[o] = (f16)(v - (float)h);
  }
}

// ---------------------------------------------------------------------------
// K3/K4: split-f16 3-product MFMA GEMM — round-6 config (REVERT of round 7).
//
// Round-7 post-mortem: 2-wave blocks dropped occupancy to ~9% (4 waves/CU) —
// staging-drain latency unhidden; LDS-read-traffic theory was wrong (80 MB
// at 52 TB/s aggregate = 1.5 us, never the constraint).  Round-6 config
// (4 waves 2Mx2N, 256 thr, 32 KB slots x2 = 64 KB -> 2 blocks/CU, 8
// waves/CU TLP) measured 833.6 us total — restored verbatim.
// ---------------------------------------------------------------------------
#define BKT_    32
#define NTT_    (DFC_/BKT_)   // 32 K-tiles
#define SLOT_B_ 32768         // bytes per slot
#define AH_O_   0
#define AL_O_   8192
#define BH_O_   16384
#define BL_O_   24576

template <bool SPLIT_OUT>
__global__ __launch_bounds__(256, 2) void k_gemm_f16x3(
    const f16* __restrict__ Ah, const f16* __restrict__ Al,
    const f16* __restrict__ Bh, const f16* __restrict__ Bl,
    const float* __restrict__ bias,
    f16* __restrict__ Oh, f16* __restrict__ Ol,
    const float* __restrict__ w3, float* __restrict__ part) {
  __shared__ f16 lds[2 * SLOT_B_ / 2];   // 64 KB
  char* ldsc = (char*)lds;

  // XCD swizzle: nwg = 1256 = 8*157 exactly -> simple bijective remap
  const int orig = blockIdx.x;
  const int wg = (orig & 7) * 157 + (orig >> 3);
  const int band = wg >> 3;     // 0..156
  const int nb   = wg & 7;      // 0..7
  const int r0 = band * 128;
  const int n0 = nb * 128;

  const int t = threadIdx.x;
  const int lane = t & 63, wave = t >> 6;
  const int quad = lane >> 4, lo = lane & 15;
  const int wm = wave >> 1, wn = wave & 1;

  // --- staging source byte offsets.  Plane = 128 rows x 64 B = 512 chunks
  // of 16 B; 2 passes of 256 threads.  Inverse-swizzle chunk u^((u>>3)&7)
  // (involution), then row = u'>>2 (stride 2048 B), kb = (u'&3)*16.
  const uint32_t u0 = (uint32_t)t;
  const uint32_t u1 = (uint32_t)t + 256u;
  const uint32_t us0 = u0 ^ ((u0 >> 3) & 7);
  const uint32_t us1 = u1 ^ ((u1 >> 3) & 7);
  const size_t s0 = (size_t)(us0 >> 2) * 2048 + (size_t)(us0 & 3) * 16;
  const size_t s1 = (size_t)(us1 >> 2) * 2048 + (size_t)(us1 & 3) * 16;

  const char* gAh = (const char*)Ah + (size_t)r0 * 2048;
  const char* gAl = (const char*)Al + (size_t)r0 * 2048;
  const char* gBh = (const char*)Bh + (size_t)n0 * 2048;
  const char* gBl = (const char*)Bl + (size_t)n0 * 2048;

  // --- linear gload_lds dests (bytes within slot); pass p at +p*4096
  const int d0 = t * 16;
  const int d1 = 4096 + t * 16;

  // --- swizzled ds_read offsets (bytes within 8 KB plane)
  int roffA[4], roffB[4];
  #pragma unroll
  for (int mt = 0; mt < 4; mt++) {
    int r = wm * 64 + mt * 16 + lo;
    roffA[mt] = (((r * 4 + quad) ^ ((r >> 1) & 7)) << 4);
  }
  #pragma unroll
  for (int nt = 0; nt < 4; nt++) {
    int r = wn * 64 + nt * 16 + lo;
    roffB[nt] = (((r * 4 + quad) ^ ((r >> 1) & 7)) << 4);
  }

  f32x4 acc[4][4];
  #pragma unroll
  for (int mt = 0; mt < 4; mt++)
    #pragma unroll
    for (int nt = 0; nt < 4; nt++) acc[mt][nt] = (f32x4){0.f, 0.f, 0.f, 0.f};

  // --- prologue: stage tile 0 -> slot 0 (8 loads)
  gload16(gAh + s0, ldsc + AH_O_ + d0);
  gload16(gAh + s1, ldsc + AH_O_ + d1);
  gload16(gAl + s0, ldsc + AL_O_ + d0);
  gload16(gAl + s1, ldsc + AL_O_ + d1);
  gload16(gBh + s0, ldsc + BH_O_ + d0);
  gload16(gBh + s1, ldsc + BH_O_ + d1);
  gload16(gBl + s0, ldsc + BL_O_ + d0);
  gload16(gBl + s1, ldsc + BL_O_ + d1);
  asm volatile("s_waitcnt vmcnt(0)" ::: "memory");
  __builtin_amdgcn_s_barrier();

  for (int tt = 0; tt < NTT_; ++tt) {
    const char* sc = ldsc + (tt & 1) * SLOT_B_;
    char* sw = ldsc + ((tt + 1) & 1) * SLOT_B_;
    const size_t go = (size_t)(tt + 1) * 64;   // k-byte offset of tile tt+1
    const bool pf = (tt + 1 < NTT_);

    // 1. issue next-tile staging first (slot^1 was last read at tt-1, done)
    if (pf) {
      gload16(gAh + go + s0, sw + AH_O_ + d0);
      gload16(gAh + go + s1, sw + AH_O_ + d1);
      gload16(gAl + go + s0, sw + AL_O_ + d0);
      gload16(gAl + go + s1, sw + AL_O_ + d1);
      gload16(gBh + go + s0, sw + BH_O_ + d0);
      gload16(gBh + go + s1, sw + BH_O_ + d1);
      gload16(gBl + go + s0, sw + BL_O_ + d0);
      gload16(gBl + go + s1, sw + BL_O_ + d1);
    }

    // 2. fragment reads: hi pair first so hh-MFMAs start while al/bl drain
    f16x8 ah[4], bh[4], al[4], bl[4];
    #pragma unroll
    for (int mt = 0; mt < 4; mt++)
      ah[mt] = *(const f16x8*)(sc + AH_O_ + roffA[mt]);
    #pragma unroll
    for (int nt = 0; nt < 4; nt++)
      bh[nt] = *(const f16x8*)(sc + BH_O_ + roffB[nt]);
    #pragma unroll
    for (int mt = 0; mt < 4; mt++)
      al[mt] = *(const f16x8*)(sc + AL_O_ + roffA[mt]);
    #pragma unroll
    for (int nt = 0; nt < 4; nt++)
      bl[nt] = *(const f16x8*)(sc + BL_O_ + roffB[nt]);

    // 3. 48 MFMAs — product order hh, lh, hl (bit-identical accumulation)
    __builtin_amdgcn_s_setprio(1);
    #pragma unroll
    for (int mt = 0; mt < 4; mt++)
      #pragma unroll
      for (int nt = 0; nt < 4; nt++)
        acc[mt][nt] = __builtin_amdgcn_mfma_f32_16x16x32_f16(ah[mt], bh[nt], acc[mt][nt], 0, 0, 0);
    #pragma unroll
    for (int mt = 0; mt < 4; mt++)
      #pragma unroll
      for (int nt = 0; nt < 4; nt++)
        acc[mt][nt] = __builtin_amdgcn_mfma_f32_16x16x32_f16(al[mt], bh[nt], acc[mt][nt], 0, 0, 0);
    #pragma unroll
    for (int mt = 0; mt < 4; mt++)
      #pragma unroll
      for (int nt = 0; nt < 4; nt++)
        acc[mt][nt] = __builtin_amdgcn_mfma_f32_16x16x32_f16(ah[mt], bl[nt], acc[mt][nt], 0, 0, 0);
    __builtin_amdgcn_s_setprio(0);

    // 4. tile boundary: next tile's 8 loads must have landed.  The drain
    //    stall is hidden by the co-resident second block.
    if (pf) asm volatile("s_waitcnt vmcnt(0)" ::: "memory");
    __builtin_amdgcn_s_barrier();
  }
  // loop ends with a barrier -> LDS free for epilogue staging

  if (SPLIT_OUT) {
    // wave-private 16 KB region (4 waves x 16 KB = 64 KB, fits exactly):
    // hi plane @0, lo plane @8192.  16B-chunk XOR swizzle, then full-line
    // f16x8 stores.
    char* ep = ldsc + wave * 16384;
    #pragma unroll
    for (int mt = 0; mt < 4; mt++)
      #pragma unroll
      for (int nt = 0; nt < 4; nt++) {
        const int col = n0 + wn * 64 + nt * 16 + lo;
        const float bv = bias[col];
        const int col_l = nt * 16 + lo;
        #pragma unroll
        for (int r = 0; r < 4; r++) {
          const int rl = mt * 16 + quad * 4 + r;
          float v = fmaxf(acc[mt][nt][r] + bv, 0.f);
          f16 h = (f16)v;
          f16 lw = (f16)(v - (float)h);
          const int byte = rl * 128 + ((((col_l >> 3) ^ (rl & 7)) << 4)) + (col_l & 7) * 2;
          *(f16*)(ep + byte) = h;
          *(f16*)(ep + 8192 + byte) = lw;
        }
      }
    asm volatile("s_waitcnt lgkmcnt(0)" ::: "memory");  // wave-internal
    __builtin_amdgcn_sched_barrier(0);
    const int r8 = lane >> 3;   // row within 8-row group
    const int ck = lane & 7;    // 16B chunk within row
    #pragma unroll
    for (int g = 0; g < 8; g++) {
      const int rl = g * 8 + r8;
      const int grow = r0 + wm * 64 + rl;
      const int swz = ((ck ^ (rl & 7)) << 4);
      f16x8 vh = *(const f16x8*)(ep + rl * 128 + swz);
      f16x8 vl = *(const f16x8*)(ep + 8192 + rl * 128 + swz);
      if (grow < M_) {
        const size_t gb = (size_t)grow * 2048 + (size_t)(n0 + wn * 64) * 2 + ck * 16;
        *(f16x8*)((char*)Oh + gb) = vh;
        *(f16x8*)((char*)Ol + gb) = vl;
      }
    }
  } else {
    // fused head: p[r][j] = sum over this block's 128 cols of relu(h2)*w3
    const int slot = nb * 2 + wn;   // 16 slots per row
    #pragma unroll
    for (int mt = 0; mt < 4; mt++) {
      float p[4][4];
      #pragma unroll
      for (int r = 0; r < 4; r++)
        #pragma unroll
        for (int j = 0; j < 4; j++) p[r][j] = 0.f;
      #pragma unroll
      for (int nt = 0; nt < 4; nt++) {
        const int col = n0 + wn * 64 + nt * 16 + lo;
        const float bv = bias[col];
        float4 wv = *(const float4*)(w3 + col * 4);
        #pragma unroll
        for (int r = 0; r < 4; r++) {
          float v = fmaxf(acc[mt][nt][r] + bv, 0.f);
          p[r][0] = fmaf(v, wv.x, p[r][0]);
          p[r][1] = fmaf(v, wv.y, p[r][1]);
          p[r][2] = fmaf(v, wv.z, p[r][2]);
          p[r][3] = fmaf(v, wv.w, p[r][3]);
        }
      }
      // reduce over the 16 lo-lanes (stays within the quad group)
      #pragma unroll
      for (int r = 0; r < 4; r++)
        #pragma unroll
        for (int j = 0; j < 4; j++) {
          p[r][j] += __shfl_xor(p[r][j], 1);
          p[r][j] += __shfl_xor(p[r][j], 2);
          p[r][j] += __shfl_xor(p[r][j], 4);
          p[r][j] += __shfl_xor(p[r][j], 8);
        }
      if (lo == 0) {
        const int rowb = r0 + wm * 64 + mt * 16 + quad * 4;
        #pragma unroll
        for (int r = 0; r < 4; r++)
          *(float4*)(part + ((size_t)slot * MPAD_ + rowb + r) * 4) =
              make_float4(p[r][0], p[r][1], p[r][2], p[r][3]);
      }
    }
  }
}

// ---------------------------------------------------------------------------
// K5: sum 16 logit partials + b3, softmax, keep/argmax key.  1 thread/row.
// ---------------------------------------------------------------------------
__global__ __launch_bounds__(256) void k_head2(const float* __restrict__ part,
                                               const float* __restrict__ b3,
                                               float* __restrict__ s_out,
                                               int* __restrict__ key_out) {
  const int row = blockIdx.x * 256 + threadIdx.x;
  if (row >= M_) return;
  float l0 = b3[0], l1 = b3[1], l2 = b3[2], l3 = b3[3];
  #pragma unroll
  for (int sl = 0; sl < 16; sl++) {
    float4 p = *(const float4*)(part + ((size_t)sl * MPAD_ + row) * 4);
    l0 += p.x; l1 += p.y; l2 += p.z; l3 += p.w;
  }
  float mx = fmaxf(fmaxf(l0, l1), fmaxf(l2, l3));
  float e0 = expf(l0 - mx), e1 = expf(l1 - mx), e2 = expf(l2 - mx), e3 = expf(l3 - mx);
  float inv = 1.f / (e0 + e1 + e2 + e3);
  float s0 = e0 * inv, s1 = e1 * inv, s2 = e2 * inv, s3 = e3 * inv;
  *(float4*)(s_out + (size_t)row * 4) = make_float4(s0, s1, s2, s3);
  bool keep = ((s1 > 0.25f) || (s2 > 0.25f) || (s3 > 0.25f)) && (s0 < 0.25f);
  int am = 0; float best = s0;
  if (s1 > best) { best = s1; am = 1; }
  if (s2 > best) { best = s2; am = 2; }
  if (s3 > best) { best = s3; am = 3; }
  key_out[row] = keep ? am : -1;
}

// ---------------------------------------------------------------------------
// K6: per-batch stable counting sort (5 classes) + cyclic select.
// ---------------------------------------------------------------------------
__global__ __launch_bounds__(1024) void k_select(const int* __restrict__ key,
                                                 const float* __restrict__ lines,
                                                 const float* __restrict__ s,
                                                 float* __restrict__ out_lines,
                                                 float* __restrict__ out_score) {
  __shared__ int s_ord[L_];
  __shared__ int s_scan[1024];
  __shared__ int s_tot[5];
  const int b = blockIdx.x;
  const int t = threadIdx.x;
  const int base_l = t * 5;
  int cls[5];
  int c[5] = {0, 0, 0, 0, 0};
  #pragma unroll
  for (int i = 0; i < 5; i++) {
    int l = base_l + i;
    int cl = -1;
    if (l < L_) {
      int k = key[b * L_ + l];
      cl = (k < 0) ? 4 : (3 - k);
      c[cl]++;
    }
    cls[i] = cl;
  }
  int pf[5];
  for (int cc = 0; cc < 5; cc++) {
    s_scan[t] = c[cc];
    __syncthreads();
    for (int off = 1; off < 1024; off <<= 1) {
      int add = (t >= off) ? s_scan[t - off] : 0;
      __syncthreads();
      s_scan[t] += add;
      __syncthreads();
    }
    pf[cc] = s_scan[t] - c[cc];
    if (t == 1023) s_tot[cc] = s_scan[1023];
    __syncthreads();
  }
  int basec[5];
  basec[0] = 0;
  #pragma unroll
  for (int cc = 1; cc < 5; cc++) basec[cc] = basec[cc - 1] + s_tot[cc - 1];
  int run[5] = {0, 0, 0, 0, 0};
  #pragma unroll
  for (int i = 0; i < 5; i++) {
    if (cls[i] >= 0) {
      int cl = cls[i];
      int pos = basec[cl] + pf[cl] + run[cl];
      run[cl]++;
      s_ord[pos] = base_l + i;
    }
  }
  const int cnt = L_ - s_tot[4];
  __syncthreads();
  for (int j = t; j < NOUT_; j += 1024) {
    float4 lv = make_float4(0.f, 0.f, 0.f, 0.f);
    float4 sv = make_float4(0.f, 0.f, 0.f, 0.f);
    if (cnt > 0) {
      int idx = s_ord[j % cnt];
      lv = *(const float4*)(lines + (size_t)(b * L_ + idx) * 4);
      sv = *(const float4*)(s + (size_t)(b * L_ + idx) * 4);
    }
    *(float4*)(out_lines + (size_t)(b * NOUT_ + j) * 4) = lv;
    *(float4*)(out_score + (size_t)(b * NOUT_ + j) * 4) = sv;
  }
}

// ---------------------------------------------------------------------------
extern "C" void kernel_launch(void* const* d_in, const int* in_sizes, int n_in,
                              void* d_out, int out_size, void* d_ws, size_t ws_size,
                              hipStream_t stream) {
  const float* feature = (const float*)d_in[0];
  const float* lines   = (const float*)d_in[1];
  const float* fc1_w   = (const float*)d_in[2];
  const float* fc1_b   = (const float*)d_in[3];
  const float* w1      = (const float*)d_in[4];
  const float* b1      = (const float*)d_in[5];
  const float* w2      = (const float*)d_in[6];
  const float* b2      = (const float*)d_in[7];
  const float* w3      = (const float*)d_in[8];
  const float* b3      = (const float*)d_in[9];

  float* out_lines = (float*)d_out;
  float* out_score = out_lines + B_ * NOUT_ * 4;
  float* s_out     = out_score + B_ * NOUT_ * 4;

  // workspace layout (bytes): see prior rounds (unchanged).
  char* ws = (char*)d_ws;
  float* x    = (float*)(ws);
  f16*   h1h  = (f16*)(ws);
  f16*   h1l  = (f16*)(ws + 41156608ull);
  float* part = (float*)(ws + 82313216ull);
  f16*   fh   = (f16*)(ws + 134217728ull);
  f16*   fl   = (f16*)(ws + 134217728ull + 41156608ull);
  f16*   wt1h = (f16*)(ws + 216530944ull);
  f16*   wt1l = (f16*)(ws + 216530944ull + 2097152ull);
  f16*   wt2h = (f16*)(ws + 216530944ull + 2ull * 2097152ull);
  f16*   wt2l = (f16*)(ws + 216530944ull + 3ull * 2097152ull);
  int*   keys = (int*)(ws + 224919552ull);
  f16*   wc_h = (f16*)(ws + 224999552ull);
  f16*   wc_l = (f16*)(ws + 224999552ull + 65536ull);

  k_order<<<dim3(B_), 1024, 0, stream>>>(lines, keys);   // perm in keys buf
  k_wsplit<<<dim3(32), 256, 0, stream>>>(fc1_w, wc_h, wc_l);
  k_tsplit<<<dim3(32, 32), 256, 0, stream>>>(w1, wt1h, wt1l);
  k_tsplit<<<dim3(32, 32), 256, 0, stream>>>(w2, wt2h, wt2l);
  k_conv_mfma<<<dim3((B_ * HW_) / 128), 256, 0, stream>>>(feature, wc_h, wc_l, fc1_b, x);
  k_sample<<<dim3(M_), 128, 0, stream>>>(x, lines, keys, fh, fl);
  k_gemm_f16x3<true><<<dim3(1256), 256, 0, stream>>>(
      fh, fl, wt1h, wt1l, b1, h1h, h1l, nullptr, nullptr);
  k_gemm_f16x3<false><<<dim3(1256), 256, 0, stream>>>(
      h1h, h1l, wt2h, wt2l, b2, nullptr, nullptr, w3, part);
  k_head2<<<dim3((M_ + 255) / 256), 256, 0, stream>>>(part, b3, s_out, keys);
  k_select<<<dim3(B_), 1024, 0, stream>>>(keys, lines, s_out, out_lines, out_score);
}